// Round 1
// baseline (1904.786 us; speedup 1.0000x reference)
//
#include <hip/hip_runtime.h>

// Problem constants
constexpr int NN   = 50000;
constexpr int EE   = 800000;
constexpr int INF  = 128;   // input feat
constexpr int HIDF = 64;    // layer1 per-head
constexpr int OUTF = 32;    // layer2 per-head
constexpr int NH   = 4;     // heads

// ---------- float <-> ordered-uint encoding for atomicMax on floats ----------
__device__ __forceinline__ unsigned enc_f(float f) {
    unsigned u = __float_as_uint(f);
    return (u & 0x80000000u) ? ~u : (u | 0x80000000u);
}
__device__ __forceinline__ float dec_f(unsigned u) {
    return __uint_as_float((u & 0x80000000u) ? (u & 0x7FFFFFFFu) : ~u);
}

// ---------- Tiled fp32 GEMM: C[N,M] = A[N,K] @ B[K,M]; K%16==0, M%64==0 ----------
__global__ __launch_bounds__(256) void gemm_tiled(const float* __restrict__ A,
                                                  const float* __restrict__ B,
                                                  float* __restrict__ C,
                                                  int N, int K, int M) {
    __shared__ float As[16][68];   // [k][row], padded
    __shared__ float Bs[16][64];   // [k][col]
    const int tid = threadIdx.x;
    const int tx = tid & 15, ty = tid >> 4;
    const int row0 = blockIdx.x * 64, col0 = blockIdx.y * 64;

    float acc[4][4] = {};

    for (int k0 = 0; k0 < K; k0 += 16) {
        // A tile 64x16: each thread loads a float4 along k
        {
            const int a_row = tid >> 2;
            const int a_k   = (tid & 3) * 4;
            const int gr    = row0 + a_row;
            float4 v = make_float4(0.f, 0.f, 0.f, 0.f);
            if (gr < N) v = *(const float4*)(A + (size_t)gr * K + k0 + a_k);
            As[a_k + 0][a_row] = v.x;
            As[a_k + 1][a_row] = v.y;
            As[a_k + 2][a_row] = v.z;
            As[a_k + 3][a_row] = v.w;
        }
        // B tile 16x64
        {
            const int b_k = tid >> 4;
            const int b_c = (tid & 15) * 4;
            float4 w = *(const float4*)(B + (size_t)(k0 + b_k) * M + col0 + b_c);
            *(float4*)&Bs[b_k][b_c] = w;
        }
        __syncthreads();
        #pragma unroll
        for (int kk = 0; kk < 16; ++kk) {
            float4 a = *(const float4*)&As[kk][ty * 4];
            float4 b = *(const float4*)&Bs[kk][tx * 4];
            const float av[4] = {a.x, a.y, a.z, a.w};
            const float bv[4] = {b.x, b.y, b.z, b.w};
            #pragma unroll
            for (int i = 0; i < 4; ++i)
                #pragma unroll
                for (int j = 0; j < 4; ++j)
                    acc[i][j] = fmaf(av[i], bv[j], acc[i][j]);
        }
        __syncthreads();
    }
    #pragma unroll
    for (int i = 0; i < 4; ++i) {
        const int r = row0 + ty * 4 + i;
        if (r < N) {
            float* cp = C + (size_t)r * M + col0 + tx * 4;
            cp[0] = acc[i][0]; cp[1] = acc[i][1]; cp[2] = acc[i][2]; cp[3] = acc[i][3];
        }
    }
}

// ---------- attention scalars: a_s[p]=sum_c xl[p,c]*att_s[h,c] (p = n*H+h) ----------
template <int C>
__global__ __launch_bounds__(256) void att_scores(const float* __restrict__ xl,
                                                  const float* __restrict__ att_s,
                                                  const float* __restrict__ att_d,
                                                  float* __restrict__ a_s,
                                                  float* __restrict__ a_d) {
    const int idx = blockIdx.x * 256 + threadIdx.x;
    const int p = idx / C;   // n*H + h
    const int c = idx % C;
    if (p >= NN * NH) return;
    const int h = p & (NH - 1);
    const float v = xl[(size_t)p * C + c];
    float vs = v * att_s[h * C + c];
    float vd = v * att_d[h * C + c];
    #pragma unroll
    for (int m = C / 2; m; m >>= 1) {
        vs += __shfl_xor(vs, m, 64);
        vd += __shfl_xor(vd, m, 64);
    }
    if (c == 0) { a_s[p] = vs; a_d[p] = vd; }
}

// ---------- edge pass 1: alpha = leaky_relu(a_s[src]+a_d[dst]); segment max ----------
__global__ __launch_bounds__(256) void edge_alpha(const int* __restrict__ ei,
                                                  const float* __restrict__ a_s,
                                                  const float* __restrict__ a_d,
                                                  float* __restrict__ alpha,
                                                  unsigned* __restrict__ amax) {
    const int idx = blockIdx.x * 256 + threadIdx.x;
    if (idx >= EE * NH) return;
    const int e = idx >> 2, h = idx & 3;
    const int src = ei[e], dst = ei[EE + e];
    float a = a_s[src * NH + h] + a_d[dst * NH + h];
    a = (a > 0.f) ? a : 0.2f * a;
    alpha[idx] = a;
    atomicMax(&amax[dst * NH + h], enc_f(a));
}

// ---------- edge pass 2: ex = exp(alpha - amax[dst]); segment sum ----------
__global__ __launch_bounds__(256) void edge_expsum(const int* __restrict__ ei,
                                                   float* __restrict__ alpha,
                                                   const unsigned* __restrict__ amax,
                                                   float* __restrict__ denom) {
    const int idx = blockIdx.x * 256 + threadIdx.x;
    if (idx >= EE * NH) return;
    const int e = idx >> 2, h = idx & 3;
    const int dst = ei[EE + e];
    const float ex = expf(alpha[idx] - dec_f(amax[dst * NH + h]));
    alpha[idx] = ex;
    atomicAdd(&denom[dst * NH + h], ex);
}

// ---------- edge pass 3: scatter-add  out[dst] += (ex/denom) * xl[src] ----------
template <int HC, bool SAVE>
__global__ __launch_bounds__(256) void aggregate(const int* __restrict__ ei,
                                                 const float* __restrict__ xl,
                                                 const float* __restrict__ ex,
                                                 const float* __restrict__ denom,
                                                 float* __restrict__ outacc,
                                                 float* __restrict__ alpha_out) {
    constexpr int EPB = 256 / HC;
    constexpr int C   = HC / NH;
    const int t = threadIdx.x % HC;
    const int h = t / C;
    const int slot = blockIdx.x * EPB + threadIdx.x / HC;
    const int stride = gridDim.x * EPB;
    for (int e = slot; e < EE; e += stride) {
        const int src = ei[e], dst = ei[EE + e];
        const float w = ex[e * NH + h] / (denom[dst * NH + h] + 1e-16f);
        if (SAVE && (t % C) == 0) alpha_out[e * NH + h] = w;
        atomicAdd(&outacc[(size_t)dst * HC + t], w * xl[(size_t)src * HC + t]);
    }
}

// ---------- mean over heads + bias ----------
template <int C>
__global__ __launch_bounds__(256) void mean_bias(const float* __restrict__ acc,
                                                 const float* __restrict__ bias,
                                                 float* __restrict__ out) {
    const int idx = blockIdx.x * 256 + threadIdx.x;
    if (idx >= NN * C) return;
    const int n = idx / C, c = idx % C;
    const float* p = acc + (size_t)n * C * NH;
    out[idx] = (p[c] + p[C + c] + p[2 * C + c] + p[3 * C + c]) * 0.25f + bias[c];
}

// ---------- edge MLP: [out_src(32) | alpha(4) | out_dst(32)] @ mW1 -> relu -> @ mW2 ----------
__global__ __launch_bounds__(256) void edge_mlp(const float* __restrict__ nodes,  // [N,32]
                                                const float* __restrict__ alpha,  // [E,4]
                                                const int* __restrict__ ei,
                                                const float* __restrict__ mW1,    // [68,64]
                                                const float* __restrict__ mb1,    // [64]
                                                const float* __restrict__ mW2,    // [64,2]
                                                const float* __restrict__ mb2,    // [2]
                                                float* __restrict__ out) {        // [E,2]
    __shared__ float w1s[68 * 64];
    __shared__ float b1s[64];
    __shared__ float w2s[128];
    __shared__ float feat[4][72];
    const int tid = threadIdx.x;
    for (int i = tid; i < 68 * 64; i += 256) w1s[i] = mW1[i];
    if (tid < 64)  b1s[tid] = mb1[tid];
    if (tid < 128) w2s[tid] = mW2[tid];
    __syncthreads();
    const float bo0 = mb2[0], bo1 = mb2[1];

    const int wave = tid >> 6, lane = tid & 63;
    const int gwave = blockIdx.x * 4 + wave;
    const int nwaves = gridDim.x * 4;
    const int iters = (EE + nwaves - 1) / nwaves;

    for (int it = 0; it < iters; ++it) {
        const int e = it * nwaves + gwave;
        if (e < EE) {
            const int src = ei[e];
            const int dst = ei[EE + e];
            if (lane < 32) feat[wave][lane] = nodes[src * 32 + lane];
            else           feat[wave][4 + lane] = nodes[dst * 32 + (lane - 32)];  // 36..67
            if (lane >= 32 && lane < 36) feat[wave][lane] = alpha[e * NH + (lane - 32)];
        }
        __syncthreads();
        if (e < EE) {
            float accv = b1s[lane];
            #pragma unroll
            for (int k = 0; k < 68; ++k)
                accv = fmaf(feat[wave][k], w1s[k * 64 + lane], accv);
            accv = fmaxf(accv, 0.f);
            float v0 = accv * w2s[lane * 2 + 0];
            float v1 = accv * w2s[lane * 2 + 1];
            #pragma unroll
            for (int m = 32; m; m >>= 1) {
                v0 += __shfl_xor(v0, m, 64);
                v1 += __shfl_xor(v1, m, 64);
            }
            if (lane == 0) {
                out[(size_t)e * 2 + 0] = v0 + bo0;
                out[(size_t)e * 2 + 1] = v1 + bo1;
            }
        }
        __syncthreads();
    }
}

extern "C" void kernel_launch(void* const* d_in, const int* in_sizes, int n_in,
                              void* d_out, int out_size, void* d_ws, size_t ws_size,
                              hipStream_t stream) {
    const float* x        = (const float*)d_in[0];
    const int*   ei       = (const int*)d_in[1];
    // d_in[2] edge_attr: unused (edge_dim=None). d_in[3] flag: unused.
    const float* W1       = (const float*)d_in[4];
    const float* att1_src = (const float*)d_in[5];
    const float* att1_dst = (const float*)d_in[6];
    const float* b1       = (const float*)d_in[7];
    const float* W3       = (const float*)d_in[8];
    const float* att3_src = (const float*)d_in[9];
    const float* att3_dst = (const float*)d_in[10];
    const float* b3       = (const float*)d_in[11];
    const float* mW1      = (const float*)d_in[12];
    const float* mb1      = (const float*)d_in[13];
    const float* mW2      = (const float*)d_in[14];
    const float* mb2      = (const float*)d_in[15];

    float* out_nodes = (float*)d_out;               // [N,32]
    float* out_edges = out_nodes + (size_t)NN * 32; // [E,2]

    // workspace layout (floats), buffers reused across layers; ~144 MB total
    float* ws = (float*)d_ws;
    float*    xl     = ws;                               // max N*256
    float*    outacc = ws + 12800000;                    // max N*256
    float*    exbuf  = ws + 25600000;                    // E*4
    float*    h1     = ws + 28800000;                    // N*64
    float*    an2    = ws + 32000000;                    // E*4 (layer2 alpha_n)
    float*    a_s    = ws + 35200000;                    // N*4
    float*    a_d    = ws + 35400000;                    // N*4
    float*    den    = ws + 35600000;                    // N*4
    unsigned* amax   = (unsigned*)(ws + 35800000);       // N*4

    const int gemmRows = (NN + 63) / 64;  // 782

    // ======== Layer 1 (C=64, HC=256) ========
    hipMemsetAsync(outacc, 0, (size_t)NN * 256 * 4, stream);
    hipMemsetAsync(den,    0, (size_t)NN * NH * 4, stream);
    hipMemsetAsync(amax,   0, (size_t)NN * NH * 4, stream);

    gemm_tiled<<<dim3(gemmRows, 4), 256, 0, stream>>>(x, W1, xl, NN, INF, NH * HIDF);
    att_scores<64><<<(NN * NH * 64) / 256, 256, 0, stream>>>(xl, att1_src, att1_dst, a_s, a_d);
    edge_alpha<<<(EE * NH) / 256, 256, 0, stream>>>(ei, a_s, a_d, exbuf, amax);
    edge_expsum<<<(EE * NH) / 256, 256, 0, stream>>>(ei, exbuf, amax, den);
    aggregate<256, false><<<25000, 256, 0, stream>>>(ei, xl, exbuf, den, outacc, nullptr);
    mean_bias<64><<<(NN * 64) / 256, 256, 0, stream>>>(outacc, b1, h1);

    // ======== Layer 2 (C=32, HC=128) ========
    hipMemsetAsync(outacc, 0, (size_t)NN * 128 * 4, stream);
    hipMemsetAsync(den,    0, (size_t)NN * NH * 4, stream);
    hipMemsetAsync(amax,   0, (size_t)NN * NH * 4, stream);

    gemm_tiled<<<dim3(gemmRows, 2), 256, 0, stream>>>(h1, W3, xl, NN, HIDF, NH * OUTF);
    att_scores<32><<<(NN * NH * 32) / 256, 256, 0, stream>>>(xl, att3_src, att3_dst, a_s, a_d);
    edge_alpha<<<(EE * NH) / 256, 256, 0, stream>>>(ei, a_s, a_d, exbuf, amax);
    edge_expsum<<<(EE * NH) / 256, 256, 0, stream>>>(ei, exbuf, amax, den);
    aggregate<128, true><<<25000, 256, 0, stream>>>(ei, xl, exbuf, den, outacc, an2);
    mean_bias<32><<<(NN * 32) / 256, 256, 0, stream>>>(outacc, b3, out_nodes);

    // ======== Edge MLP ========
    edge_mlp<<<2048, 256, 0, stream>>>(out_nodes, an2, ei, mW1, mb1, mW2, mb2, out_edges);
}

// Round 2
// 1228.082 us; speedup vs baseline: 1.5510x; 1.5510x over previous
//
#include <hip/hip_runtime.h>

// Problem constants
constexpr int NN   = 50000;
constexpr int EE   = 800000;
constexpr int INF  = 128;   // input feat
constexpr int NH   = 4;     // heads

// ---------- float <-> ordered-uint encoding for atomicMax on floats ----------
__device__ __forceinline__ unsigned enc_f(float f) {
    unsigned u = __float_as_uint(f);
    return (u & 0x80000000u) ? ~u : (u | 0x80000000u);
}
__device__ __forceinline__ float dec_f(unsigned u) {
    return __uint_as_float((u & 0x80000000u) ? (u & 0x7FFFFFFFu) : ~u);
}

// ---------- Tiled fp32 GEMM: C[N,M] = A[N,K] @ B[K,M]; K%16==0, M%64==0 ----------
__global__ __launch_bounds__(256) void gemm_tiled(const float* __restrict__ A,
                                                  const float* __restrict__ B,
                                                  float* __restrict__ C,
                                                  int N, int K, int M) {
    __shared__ float As[16][68];   // [k][row], padded
    __shared__ float Bs[16][64];   // [k][col]
    const int tid = threadIdx.x;
    const int tx = tid & 15, ty = tid >> 4;
    const int row0 = blockIdx.x * 64, col0 = blockIdx.y * 64;

    float acc[4][4] = {};

    for (int k0 = 0; k0 < K; k0 += 16) {
        {
            const int a_row = tid >> 2;
            const int a_k   = (tid & 3) * 4;
            const int gr    = row0 + a_row;
            float4 v = make_float4(0.f, 0.f, 0.f, 0.f);
            if (gr < N) v = *(const float4*)(A + (size_t)gr * K + k0 + a_k);
            As[a_k + 0][a_row] = v.x;
            As[a_k + 1][a_row] = v.y;
            As[a_k + 2][a_row] = v.z;
            As[a_k + 3][a_row] = v.w;
        }
        {
            const int b_k = tid >> 4;
            const int b_c = (tid & 15) * 4;
            float4 w = *(const float4*)(B + (size_t)(k0 + b_k) * M + col0 + b_c);
            *(float4*)&Bs[b_k][b_c] = w;
        }
        __syncthreads();
        #pragma unroll
        for (int kk = 0; kk < 16; ++kk) {
            float4 a = *(const float4*)&As[kk][ty * 4];
            float4 b = *(const float4*)&Bs[kk][tx * 4];
            const float av[4] = {a.x, a.y, a.z, a.w};
            const float bv[4] = {b.x, b.y, b.z, b.w};
            #pragma unroll
            for (int i = 0; i < 4; ++i)
                #pragma unroll
                for (int j = 0; j < 4; ++j)
                    acc[i][j] = fmaf(av[i], bv[j], acc[i][j]);
        }
        __syncthreads();
    }
    #pragma unroll
    for (int i = 0; i < 4; ++i) {
        const int r = row0 + ty * 4 + i;
        if (r < N) {
            float* cp = C + (size_t)r * M + col0 + tx * 4;
            cp[0] = acc[i][0]; cp[1] = acc[i][1]; cp[2] = acc[i][2]; cp[3] = acc[i][3];
        }
    }
}

// ---------- CSR build ----------
__global__ __launch_bounds__(256) void count_deg_k(const int* __restrict__ ei,
                                                   int* __restrict__ deg) {
    const int e = blockIdx.x * 256 + threadIdx.x;
    if (e < EE) atomicAdd(&deg[ei[EE + e]], 1);
}

// single-block exclusive scan over deg[0..NN) -> rowptr[0..NN], cursor copy
__global__ __launch_bounds__(1024) void scan_k(const int* __restrict__ deg,
                                               int* __restrict__ rowptr,
                                               int* __restrict__ cursor) {
    __shared__ int wsum[16];
    const int tid = threadIdx.x;
    const int lane = tid & 63, wv = tid >> 6;
    int total = 0;
    for (int base = 0; base < NN; base += 1024) {
        const int i = base + tid;
        const int v = (i < NN) ? deg[i] : 0;
        int incl = v;
        #pragma unroll
        for (int d = 1; d < 64; d <<= 1) {
            int t = __shfl_up(incl, d, 64);
            if (lane >= d) incl += t;
        }
        if (lane == 63) wsum[wv] = incl;
        __syncthreads();
        if (wv == 0) {
            int s = (lane < 16) ? wsum[lane] : 0;
            #pragma unroll
            for (int d = 1; d < 16; d <<= 1) {
                int t = __shfl_up(s, d, 64);
                if (lane >= d) s += t;
            }
            if (lane < 16) wsum[lane] = s;
        }
        __syncthreads();
        const int excl = total + (wv > 0 ? wsum[wv - 1] : 0) + incl - v;
        const int chunk = wsum[15];
        if (i < NN) { rowptr[i] = excl; cursor[i] = excl; }
        total += chunk;
        __syncthreads();   // protect wsum before next iteration's writes
    }
    if (tid == 0) rowptr[NN] = total;
}

__global__ __launch_bounds__(256) void scatter_perm_k(const int* __restrict__ ei,
                                                      int* __restrict__ cursor,
                                                      int* __restrict__ perm,
                                                      int* __restrict__ psrc) {
    const int e = blockIdx.x * 256 + threadIdx.x;
    if (e >= EE) return;
    const int d = ei[EE + e];
    const int p = atomicAdd(&cursor[d], 1);
    perm[p] = e;
    psrc[p] = ei[e];
}

// ---------- attention scalars: a_s[p]=sum_c xl[p,c]*att_s[h,c] (p = n*H+h) ----------
template <int C>
__global__ __launch_bounds__(256) void att_scores(const float* __restrict__ xl,
                                                  const float* __restrict__ att_s,
                                                  const float* __restrict__ att_d,
                                                  float* __restrict__ a_s,
                                                  float* __restrict__ a_d) {
    const int idx = blockIdx.x * 256 + threadIdx.x;
    const int p = idx / C;   // n*H + h
    const int c = idx % C;
    if (p >= NN * NH) return;
    const int h = p & (NH - 1);
    const float v = xl[(size_t)p * C + c];
    float vs = v * att_s[h * C + c];
    float vd = v * att_d[h * C + c];
    #pragma unroll
    for (int m = C / 2; m; m >>= 1) {
        vs += __shfl_xor(vs, m, 64);
        vd += __shfl_xor(vd, m, 64);
    }
    if (c == 0) { a_s[p] = vs; a_d[p] = vd; }
}

// ---------- edge pass 1: alpha = leaky_relu(a_s[src]+a_d[dst]); segment max ----------
__global__ __launch_bounds__(256) void edge_alpha(const int* __restrict__ ei,
                                                  const float* __restrict__ a_s,
                                                  const float* __restrict__ a_d,
                                                  float* __restrict__ alpha,
                                                  unsigned* __restrict__ amax) {
    const int idx = blockIdx.x * 256 + threadIdx.x;
    if (idx >= EE * NH) return;
    const int e = idx >> 2, h = idx & 3;
    const int src = ei[e], dst = ei[EE + e];
    float a = a_s[src * NH + h] + a_d[dst * NH + h];
    a = (a > 0.f) ? a : 0.2f * a;
    alpha[idx] = a;
    atomicMax(&amax[dst * NH + h], enc_f(a));
}

// ---------- edge pass 2: ex = exp(alpha - amax[dst]); segment sum ----------
__global__ __launch_bounds__(256) void edge_expsum(const int* __restrict__ ei,
                                                   float* __restrict__ alpha,
                                                   const unsigned* __restrict__ amax,
                                                   float* __restrict__ denom) {
    const int idx = blockIdx.x * 256 + threadIdx.x;
    if (idx >= EE * NH) return;
    const int e = idx >> 2, h = idx & 3;
    const int dst = ei[EE + e];
    const float ex = expf(alpha[idx] - dec_f(amax[dst * NH + h]));
    alpha[idx] = ex;
    atomicAdd(&denom[dst * NH + h], ex);
}

// ---------- normalize: alpha_p[j,h] = ex[perm[j],h]/denom ; optionally orig order ----------
template <bool WRITE_ORIG>
__global__ __launch_bounds__(256) void normalize_perm(const int* __restrict__ perm,
                                                      const int* __restrict__ ei,
                                                      const float* __restrict__ ex,
                                                      const float* __restrict__ den,
                                                      float* __restrict__ alpha_p,
                                                      float* __restrict__ alpha_orig) {
    const int idx = blockIdx.x * 256 + threadIdx.x;
    if (idx >= EE * NH) return;
    const int j = idx >> 2, h = idx & 3;
    const int e = perm[j];
    const int dst = ei[EE + e];
    const float w = ex[e * NH + h] / (den[dst * NH + h] + 1e-16f);
    alpha_p[idx] = w;
    if (WRITE_ORIG) alpha_orig[e * NH + h] = w;
}

// ---------- CSR aggregate + head-mean + bias: one block per dst node ----------
template <int C>   // per-head channels (64 for L1, 32 for L2)
__global__ __launch_bounds__(NH * C) void aggregate_csr(const int* __restrict__ rowptr,
                                                        const int* __restrict__ psrc,
                                                        const float* __restrict__ alpha_p,
                                                        const float* __restrict__ xl,
                                                        const float* __restrict__ bias,
                                                        float* __restrict__ out) {
    constexpr int HC = NH * C;
    __shared__ float red[HC];
    const int n = blockIdx.x;
    const int t = threadIdx.x;
    const int h = t / C;
    const int r0 = rowptr[n], r1 = rowptr[n + 1];
    float acc0 = 0.f, acc1 = 0.f;
    int j = r0;
    for (; j + 1 < r1; j += 2) {
        const int s0 = psrc[j];
        const int s1 = psrc[j + 1];
        const float w0 = alpha_p[j * NH + h];
        const float w1 = alpha_p[(j + 1) * NH + h];
        acc0 = fmaf(w0, xl[(size_t)s0 * HC + t], acc0);
        acc1 = fmaf(w1, xl[(size_t)s1 * HC + t], acc1);
    }
    if (j < r1) {
        const int s0 = psrc[j];
        const float w0 = alpha_p[j * NH + h];
        acc0 = fmaf(w0, xl[(size_t)s0 * HC + t], acc0);
    }
    red[t] = acc0 + acc1;
    __syncthreads();
    if (t < C) {
        out[(size_t)n * C + t] =
            (red[t] + red[t + C] + red[t + 2 * C] + red[t + 3 * C]) * 0.25f + bias[t];
    }
}

// ---------- edge MLP: [out_src(32) | alpha(4) | out_dst(32)] @ mW1 -> relu -> @ mW2 ----------
__global__ __launch_bounds__(256) void edge_mlp(const float* __restrict__ nodes,  // [N,32]
                                                const float* __restrict__ alpha,  // [E,4]
                                                const int* __restrict__ ei,
                                                const float* __restrict__ mW1,    // [68,64]
                                                const float* __restrict__ mb1,    // [64]
                                                const float* __restrict__ mW2,    // [64,2]
                                                const float* __restrict__ mb2,    // [2]
                                                float* __restrict__ out) {        // [E,2]
    __shared__ float w1s[68 * 64];
    __shared__ float b1s[64];
    __shared__ float w2s[128];
    __shared__ float feat[4][72];
    const int tid = threadIdx.x;
    for (int i = tid; i < 68 * 64; i += 256) w1s[i] = mW1[i];
    if (tid < 64)  b1s[tid] = mb1[tid];
    if (tid < 128) w2s[tid] = mW2[tid];
    __syncthreads();
    const float bo0 = mb2[0], bo1 = mb2[1];

    const int wave = tid >> 6, lane = tid & 63;
    const int gwave = blockIdx.x * 4 + wave;
    const int nwaves = gridDim.x * 4;
    const int iters = (EE + nwaves - 1) / nwaves;

    for (int it = 0; it < iters; ++it) {
        const int e = it * nwaves + gwave;
        if (e < EE) {
            const int src = ei[e];
            const int dst = ei[EE + e];
            if (lane < 32) feat[wave][lane] = nodes[src * 32 + lane];
            else           feat[wave][4 + lane] = nodes[dst * 32 + (lane - 32)];  // 36..67
            if (lane >= 32 && lane < 36) feat[wave][lane] = alpha[e * NH + (lane - 32)];
        }
        __syncthreads();
        if (e < EE) {
            float accv = b1s[lane];
            #pragma unroll
            for (int k = 0; k < 68; ++k)
                accv = fmaf(feat[wave][k], w1s[k * 64 + lane], accv);
            accv = fmaxf(accv, 0.f);
            float v0 = accv * w2s[lane * 2 + 0];
            float v1 = accv * w2s[lane * 2 + 1];
            #pragma unroll
            for (int m = 32; m; m >>= 1) {
                v0 += __shfl_xor(v0, m, 64);
                v1 += __shfl_xor(v1, m, 64);
            }
            if (lane == 0) {
                out[(size_t)e * 2 + 0] = v0 + bo0;
                out[(size_t)e * 2 + 1] = v1 + bo1;
            }
        }
        __syncthreads();
    }
}

extern "C" void kernel_launch(void* const* d_in, const int* in_sizes, int n_in,
                              void* d_out, int out_size, void* d_ws, size_t ws_size,
                              hipStream_t stream) {
    const float* x        = (const float*)d_in[0];
    const int*   ei       = (const int*)d_in[1];
    // d_in[2] edge_attr: unused (edge_dim=None). d_in[3] flag: unused.
    const float* W1       = (const float*)d_in[4];
    const float* att1_src = (const float*)d_in[5];
    const float* att1_dst = (const float*)d_in[6];
    const float* b1       = (const float*)d_in[7];
    const float* W3       = (const float*)d_in[8];
    const float* att3_src = (const float*)d_in[9];
    const float* att3_dst = (const float*)d_in[10];
    const float* b3       = (const float*)d_in[11];
    const float* mW1      = (const float*)d_in[12];
    const float* mb1      = (const float*)d_in[13];
    const float* mW2      = (const float*)d_in[14];
    const float* mb2      = (const float*)d_in[15];

    float* out_nodes = (float*)d_out;               // [N,32]
    float* out_edges = out_nodes + (size_t)NN * 32; // [E,2]

    // workspace layout (floats/ints) — ~115 MB
    float* ws = (float*)d_ws;
    float*    xl      = ws;                           // N*256 = 12.8M
    float*    h1      = ws + 12800000;                // N*64  = 3.2M
    float*    exbuf   = ws + 16000000;                // E*4   = 3.2M
    float*    alpha_p = ws + 19200000;                // E*4   = 3.2M (permuted alpha_n)
    float*    an2     = ws + 22400000;                // E*4   = 3.2M (orig-order L2 alpha_n)
    float*    a_s     = ws + 25600000;                // N*4
    float*    a_d     = ws + 25800000;                // N*4
    float*    den     = ws + 26000000;                // N*4
    unsigned* amax    = (unsigned*)(ws + 26200000);   // N*4
    int*      deg     = (int*)(ws + 26400000);        // N
    int*      cursor  = (int*)(ws + 26450000);        // N
    int*      rowptr  = (int*)(ws + 26500000);        // N+1
    int*      perm    = (int*)(ws + 26550008);        // E
    int*      psrc    = (int*)(ws + 27350008);        // E

    const int gemmRows = (NN + 63) / 64;  // 782
    const int EB = (EE + 255) / 256;      // 3125

    // ======== CSR build (shared by both layers) ========
    hipMemsetAsync(deg, 0, (size_t)NN * 4, stream);
    count_deg_k<<<EB, 256, 0, stream>>>(ei, deg);
    scan_k<<<1, 1024, 0, stream>>>(deg, rowptr, cursor);
    scatter_perm_k<<<EB, 256, 0, stream>>>(ei, cursor, perm, psrc);

    // ======== Layer 1 (C=64, HC=256) ========
    hipMemsetAsync(den,  0, (size_t)NN * NH * 4, stream);
    hipMemsetAsync(amax, 0, (size_t)NN * NH * 4, stream);

    gemm_tiled<<<dim3(gemmRows, 4), 256, 0, stream>>>(x, W1, xl, NN, INF, NH * 64);
    att_scores<64><<<(NN * NH * 64) / 256, 256, 0, stream>>>(xl, att1_src, att1_dst, a_s, a_d);
    edge_alpha<<<(EE * NH) / 256, 256, 0, stream>>>(ei, a_s, a_d, exbuf, amax);
    edge_expsum<<<(EE * NH) / 256, 256, 0, stream>>>(ei, exbuf, amax, den);
    normalize_perm<false><<<(EE * NH) / 256, 256, 0, stream>>>(perm, ei, exbuf, den, alpha_p, nullptr);
    aggregate_csr<64><<<NN, 256, 0, stream>>>(rowptr, psrc, alpha_p, xl, b1, h1);

    // ======== Layer 2 (C=32, HC=128) ========
    hipMemsetAsync(den,  0, (size_t)NN * NH * 4, stream);
    hipMemsetAsync(amax, 0, (size_t)NN * NH * 4, stream);

    gemm_tiled<<<dim3(gemmRows, 2), 256, 0, stream>>>(h1, W3, xl, NN, 64, NH * 32);
    att_scores<32><<<(NN * NH * 32) / 256, 256, 0, stream>>>(xl, att3_src, att3_dst, a_s, a_d);
    edge_alpha<<<(EE * NH) / 256, 256, 0, stream>>>(ei, a_s, a_d, exbuf, amax);
    edge_expsum<<<(EE * NH) / 256, 256, 0, stream>>>(ei, exbuf, amax, den);
    normalize_perm<true><<<(EE * NH) / 256, 256, 0, stream>>>(perm, ei, exbuf, den, alpha_p, an2);
    aggregate_csr<32><<<NN, 128, 0, stream>>>(rowptr, psrc, alpha_p, xl, b3, out_nodes);

    // ======== Edge MLP ========
    edge_mlp<<<2048, 256, 0, stream>>>(out_nodes, an2, ei, mW1, mb1, mW2, mb2, out_edges);
}

// Round 3
// 842.047 us; speedup vs baseline: 2.2621x; 1.4584x over previous
//
#include <hip/hip_runtime.h>

// Problem constants
constexpr int NN   = 50000;
constexpr int EE   = 800000;
constexpr int INF  = 128;   // input feat
constexpr int NH   = 4;     // heads

// ---------- float <-> ordered-uint encoding for atomicMax on floats ----------
__device__ __forceinline__ unsigned enc_f(float f) {
    unsigned u = __float_as_uint(f);
    return (u & 0x80000000u) ? ~u : (u | 0x80000000u);
}
__device__ __forceinline__ float dec_f(unsigned u) {
    return __uint_as_float((u & 0x80000000u) ? (u & 0x7FFFFFFFu) : ~u);
}

// ---------- Tiled fp32 GEMM: C[N,M] = A[N,K] @ B[K,M]; K%16==0, M%64==0 ----------
__global__ __launch_bounds__(256) void gemm_tiled(const float* __restrict__ A,
                                                  const float* __restrict__ B,
                                                  float* __restrict__ C,
                                                  int N, int K, int M) {
    __shared__ float As[16][68];   // [k][row], padded
    __shared__ float Bs[16][64];   // [k][col]
    const int tid = threadIdx.x;
    const int tx = tid & 15, ty = tid >> 4;
    const int row0 = blockIdx.x * 64, col0 = blockIdx.y * 64;

    float acc[4][4] = {};

    for (int k0 = 0; k0 < K; k0 += 16) {
        {
            const int a_row = tid >> 2;
            const int a_k   = (tid & 3) * 4;
            const int gr    = row0 + a_row;
            float4 v = make_float4(0.f, 0.f, 0.f, 0.f);
            if (gr < N) v = *(const float4*)(A + (size_t)gr * K + k0 + a_k);
            As[a_k + 0][a_row] = v.x;
            As[a_k + 1][a_row] = v.y;
            As[a_k + 2][a_row] = v.z;
            As[a_k + 3][a_row] = v.w;
        }
        {
            const int b_k = tid >> 4;
            const int b_c = (tid & 15) * 4;
            float4 w = *(const float4*)(B + (size_t)(k0 + b_k) * M + col0 + b_c);
            *(float4*)&Bs[b_k][b_c] = w;
        }
        __syncthreads();
        #pragma unroll
        for (int kk = 0; kk < 16; ++kk) {
            float4 a = *(const float4*)&As[kk][ty * 4];
            float4 b = *(const float4*)&Bs[kk][tx * 4];
            const float av[4] = {a.x, a.y, a.z, a.w};
            const float bv[4] = {b.x, b.y, b.z, b.w};
            #pragma unroll
            for (int i = 0; i < 4; ++i)
                #pragma unroll
                for (int j = 0; j < 4; ++j)
                    acc[i][j] = fmaf(av[i], bv[j], acc[i][j]);
        }
        __syncthreads();
    }
    #pragma unroll
    for (int i = 0; i < 4; ++i) {
        const int r = row0 + ty * 4 + i;
        if (r < N) {
            float* cp = C + (size_t)r * M + col0 + tx * 4;
            cp[0] = acc[i][0]; cp[1] = acc[i][1]; cp[2] = acc[i][2]; cp[3] = acc[i][3];
        }
    }
}

// ---------- CSR build ----------
__global__ __launch_bounds__(256) void count_deg_k(const int* __restrict__ ei,
                                                   int* __restrict__ deg) {
    const int e = blockIdx.x * 256 + threadIdx.x;
    if (e < EE) atomicAdd(&deg[ei[EE + e]], 1);
}

// single-block exclusive scan over deg[0..NN) -> rowptr[0..NN], cursor copy
__global__ __launch_bounds__(1024) void scan_k(const int* __restrict__ deg,
                                               int* __restrict__ rowptr,
                                               int* __restrict__ cursor) {
    __shared__ int wsum[16];
    const int tid = threadIdx.x;
    const int lane = tid & 63, wv = tid >> 6;
    int total = 0;
    for (int base = 0; base < NN; base += 1024) {
        const int i = base + tid;
        const int v = (i < NN) ? deg[i] : 0;
        int incl = v;
        #pragma unroll
        for (int d = 1; d < 64; d <<= 1) {
            int t = __shfl_up(incl, d, 64);
            if (lane >= d) incl += t;
        }
        if (lane == 63) wsum[wv] = incl;
        __syncthreads();
        if (wv == 0) {
            int s = (lane < 16) ? wsum[lane] : 0;
            #pragma unroll
            for (int d = 1; d < 16; d <<= 1) {
                int t = __shfl_up(s, d, 64);
                if (lane >= d) s += t;
            }
            if (lane < 16) wsum[lane] = s;
        }
        __syncthreads();
        const int excl = total + (wv > 0 ? wsum[wv - 1] : 0) + incl - v;
        const int chunk = wsum[15];
        if (i < NN) { rowptr[i] = excl; cursor[i] = excl; }
        total += chunk;
        __syncthreads();   // protect wsum before next iteration's writes
    }
    if (tid == 0) rowptr[NN] = total;
}

__global__ __launch_bounds__(256) void scatter_perm_k(const int* __restrict__ ei,
                                                      int* __restrict__ cursor,
                                                      int* __restrict__ perm,
                                                      int* __restrict__ psrc) {
    const int e = blockIdx.x * 256 + threadIdx.x;
    if (e >= EE) return;
    const int d = ei[EE + e];
    const int p = atomicAdd(&cursor[d], 1);
    perm[p] = e;
    psrc[p] = ei[e];
}

// ---------- attention scalars: a_s[p]=sum_c xl[p,c]*att_s[h,c] (p = n*H+h) ----------
template <int C>
__global__ __launch_bounds__(256) void att_scores(const float* __restrict__ xl,
                                                  const float* __restrict__ att_s,
                                                  const float* __restrict__ att_d,
                                                  float* __restrict__ a_s,
                                                  float* __restrict__ a_d) {
    const int idx = blockIdx.x * 256 + threadIdx.x;
    const int p = idx / C;   // n*H + h
    const int c = idx % C;
    if (p >= NN * NH) return;
    const int h = p & (NH - 1);
    const float v = xl[(size_t)p * C + c];
    float vs = v * att_s[h * C + c];
    float vd = v * att_d[h * C + c];
    #pragma unroll
    for (int m = C / 2; m; m >>= 1) {
        vs += __shfl_xor(vs, m, 64);
        vd += __shfl_xor(vd, m, 64);
    }
    if (c == 0) { a_s[p] = vs; a_d[p] = vd; }
}

// ---------- edge pass 1: alpha = leaky_relu(a_s[src]+a_d[dst]); segment max ----------
__global__ __launch_bounds__(256) void edge_alpha(const int* __restrict__ ei,
                                                  const float* __restrict__ a_s,
                                                  const float* __restrict__ a_d,
                                                  float* __restrict__ alpha,
                                                  unsigned* __restrict__ amax) {
    const int idx = blockIdx.x * 256 + threadIdx.x;
    if (idx >= EE * NH) return;
    const int e = idx >> 2, h = idx & 3;
    const int src = ei[e], dst = ei[EE + e];
    float a = a_s[src * NH + h] + a_d[dst * NH + h];
    a = (a > 0.f) ? a : 0.2f * a;
    alpha[idx] = a;
    atomicMax(&amax[dst * NH + h], enc_f(a));
}

// ---------- edge pass 2: ex = exp(alpha - amax[dst]); segment sum ----------
__global__ __launch_bounds__(256) void edge_expsum(const int* __restrict__ ei,
                                                   float* __restrict__ alpha,
                                                   const unsigned* __restrict__ amax,
                                                   float* __restrict__ denom) {
    const int idx = blockIdx.x * 256 + threadIdx.x;
    if (idx >= EE * NH) return;
    const int e = idx >> 2, h = idx & 3;
    const int dst = ei[EE + e];
    const float ex = expf(alpha[idx] - dec_f(amax[dst * NH + h]));
    alpha[idx] = ex;
    atomicAdd(&denom[dst * NH + h], ex);
}

// ---------- normalize: alpha_p[j,h] = ex[perm[j],h]/denom ; optionally orig order ----------
template <bool WRITE_ORIG>
__global__ __launch_bounds__(256) void normalize_perm(const int* __restrict__ perm,
                                                      const int* __restrict__ ei,
                                                      const float* __restrict__ ex,
                                                      const float* __restrict__ den,
                                                      float* __restrict__ alpha_p,
                                                      float* __restrict__ alpha_orig) {
    const int idx = blockIdx.x * 256 + threadIdx.x;
    if (idx >= EE * NH) return;
    const int j = idx >> 2, h = idx & 3;
    const int e = perm[j];
    const int dst = ei[EE + e];
    const float w = ex[e * NH + h] / (den[dst * NH + h] + 1e-16f);
    alpha_p[idx] = w;
    if (WRITE_ORIG) alpha_orig[e * NH + h] = w;
}

// ---------- CSR aggregate + head-mean + bias: one block per dst node ----------
template <int C>   // per-head channels (64 for L1, 32 for L2)
__global__ __launch_bounds__(NH * C) void aggregate_csr(const int* __restrict__ rowptr,
                                                        const int* __restrict__ psrc,
                                                        const float* __restrict__ alpha_p,
                                                        const float* __restrict__ xl,
                                                        const float* __restrict__ bias,
                                                        float* __restrict__ out) {
    constexpr int HC = NH * C;
    __shared__ float red[HC];
    const int n = blockIdx.x;
    const int t = threadIdx.x;
    const int h = t / C;
    const int r0 = rowptr[n], r1 = rowptr[n + 1];
    float acc0 = 0.f, acc1 = 0.f;
    int j = r0;
    for (; j + 1 < r1; j += 2) {
        const int s0 = psrc[j];
        const int s1 = psrc[j + 1];
        const float w0 = alpha_p[j * NH + h];
        const float w1 = alpha_p[(j + 1) * NH + h];
        acc0 = fmaf(w0, xl[(size_t)s0 * HC + t], acc0);
        acc1 = fmaf(w1, xl[(size_t)s1 * HC + t], acc1);
    }
    if (j < r1) {
        const int s0 = psrc[j];
        const float w0 = alpha_p[j * NH + h];
        acc0 = fmaf(w0, xl[(size_t)s0 * HC + t], acc0);
    }
    red[t] = acc0 + acc1;
    __syncthreads();
    if (t < C) {
        out[(size_t)n * C + t] =
            (red[t] + red[t + C] + red[t + 2 * C] + red[t + 3 * C]) * 0.25f + bias[t];
    }
}

// ---------- edge MLP as tile-GEMM ----------
// F[e][k]: k 0..31 = nodes[src][k], 32..35 = alpha[e][...], 36..67 = nodes[dst][k-36]
// h = relu(F@W1 + b1) [E,64]; out = h@W2 + b2 [E,2]
// Block: 128 edges, 128 threads. tx = tid&7 (hid octet), ty = tid>>3 (edge octet).
// Each thread: acc[8 edges][8 hid]. Two k-chunks of 34 staged k-major in LDS.
constexpr int TE = 128;          // edges per block
constexpr int FPAD = 4;          // Fs row pad (row stride 132 floats)
__global__ __launch_bounds__(128) void edge_mlp_gemm(const float* __restrict__ nodes,  // [N,32]
                                                     const float* __restrict__ alpha,  // [E,4]
                                                     const int* __restrict__ ei,
                                                     const float* __restrict__ mW1,    // [68,64]
                                                     const float* __restrict__ mb1,    // [64]
                                                     const float* __restrict__ mW2,    // [64,2]
                                                     const float* __restrict__ mb2,    // [2]
                                                     float* __restrict__ out) {        // [E,2]
    __shared__ float W1s[68 * 64];           // 17.4 KB
    __shared__ float Fs[34][TE + FPAD];      // 17.95 KB, k-major chunk

    const int tid = threadIdx.x;
    const int tx = tid & 7;      // hid group: hid = tx*8 + j
    const int ty = tid >> 3;     // edge group: e = e0 + ty*8 + i
    const int e0 = blockIdx.x * TE;
    const int e  = e0 + tid;     // gather edge for this thread

    // stage W1 (68*64 = 4352 floats = 1088 float4; 128 threads -> 8.5 rounds)
    for (int i = tid * 4; i < 68 * 64; i += 128 * 4)
        *(float4*)&W1s[i] = *(const float4*)&mW1[i];

    // per-thread second-layer weights + bias
    float w2r[8][2], b1r[8];
    #pragma unroll
    for (int j = 0; j < 8; ++j) {
        w2r[j][0] = mW2[(tx * 8 + j) * 2 + 0];
        w2r[j][1] = mW2[(tx * 8 + j) * 2 + 1];
        b1r[j]    = mb1[tx * 8 + j];
    }
    const float bo0 = mb2[0], bo1 = mb2[1];

    const int src = ei[e];
    const int dst = ei[EE + e];

    float acc[8][8] = {};

    // ---- chunk 0: k = 0..33  (src feats 0..31, alpha 0..1) ----
    {
        const float4* srow = (const float4*)(nodes + (size_t)src * 32);
        float4 v[8];
        #pragma unroll
        for (int q = 0; q < 8; ++q) v[q] = srow[q];
        const float2 al = *(const float2*)&alpha[(size_t)e * 4];
        #pragma unroll
        for (int q = 0; q < 8; ++q) {
            Fs[q * 4 + 0][tid] = v[q].x;
            Fs[q * 4 + 1][tid] = v[q].y;
            Fs[q * 4 + 2][tid] = v[q].z;
            Fs[q * 4 + 3][tid] = v[q].w;
        }
        Fs[32][tid] = al.x;
        Fs[33][tid] = al.y;
    }
    __syncthreads();
    #pragma unroll 2
    for (int k = 0; k < 34; ++k) {
        const float4 a0 = *(const float4*)&Fs[k][ty * 8];
        const float4 a1 = *(const float4*)&Fs[k][ty * 8 + 4];
        const float4 b0 = *(const float4*)&W1s[k * 64 + tx * 8];
        const float4 b1 = *(const float4*)&W1s[k * 64 + tx * 8 + 4];
        const float av[8] = {a0.x, a0.y, a0.z, a0.w, a1.x, a1.y, a1.z, a1.w};
        const float bv[8] = {b0.x, b0.y, b0.z, b0.w, b1.x, b1.y, b1.z, b1.w};
        #pragma unroll
        for (int i = 0; i < 8; ++i)
            #pragma unroll
            for (int j = 0; j < 8; ++j)
                acc[i][j] = fmaf(av[i], bv[j], acc[i][j]);
    }
    __syncthreads();

    // ---- chunk 1: k = 34..67  (alpha 2..3, dst feats 0..31) ----
    {
        const float4* drow = (const float4*)(nodes + (size_t)dst * 32);
        float4 v[8];
        #pragma unroll
        for (int q = 0; q < 8; ++q) v[q] = drow[q];
        const float2 al = *(const float2*)&alpha[(size_t)e * 4 + 2];
        Fs[0][tid] = al.x;
        Fs[1][tid] = al.y;
        #pragma unroll
        for (int q = 0; q < 8; ++q) {
            Fs[2 + q * 4 + 0][tid] = v[q].x;
            Fs[2 + q * 4 + 1][tid] = v[q].y;
            Fs[2 + q * 4 + 2][tid] = v[q].z;
            Fs[2 + q * 4 + 3][tid] = v[q].w;
        }
    }
    __syncthreads();
    #pragma unroll 2
    for (int k = 0; k < 34; ++k) {
        const float4 a0 = *(const float4*)&Fs[k][ty * 8];
        const float4 a1 = *(const float4*)&Fs[k][ty * 8 + 4];
        const float4 b0 = *(const float4*)&W1s[(34 + k) * 64 + tx * 8];
        const float4 b1 = *(const float4*)&W1s[(34 + k) * 64 + tx * 8 + 4];
        const float av[8] = {a0.x, a0.y, a0.z, a0.w, a1.x, a1.y, a1.z, a1.w};
        const float bv[8] = {b0.x, b0.y, b0.z, b0.w, b1.x, b1.y, b1.z, b1.w};
        #pragma unroll
        for (int i = 0; i < 8; ++i)
            #pragma unroll
            for (int j = 0; j < 8; ++j)
                acc[i][j] = fmaf(av[i], bv[j], acc[i][j]);
    }

    // ---- epilogue: relu + b1, layer-2 dot, reduce across tx (8 lanes), store ----
    #pragma unroll
    for (int i = 0; i < 8; ++i) {
        float v0 = 0.f, v1 = 0.f;
        #pragma unroll
        for (int j = 0; j < 8; ++j) {
            const float hv = fmaxf(acc[i][j] + b1r[j], 0.f);
            v0 = fmaf(hv, w2r[j][0], v0);
            v1 = fmaf(hv, w2r[j][1], v1);
        }
        v0 += __shfl_xor(v0, 1, 64); v0 += __shfl_xor(v0, 2, 64); v0 += __shfl_xor(v0, 4, 64);
        v1 += __shfl_xor(v1, 1, 64); v1 += __shfl_xor(v1, 2, 64); v1 += __shfl_xor(v1, 4, 64);
        if (tx == 0) {
            *(float2*)&out[(size_t)(e0 + ty * 8 + i) * 2] = make_float2(v0 + bo0, v1 + bo1);
        }
    }
}

extern "C" void kernel_launch(void* const* d_in, const int* in_sizes, int n_in,
                              void* d_out, int out_size, void* d_ws, size_t ws_size,
                              hipStream_t stream) {
    const float* x        = (const float*)d_in[0];
    const int*   ei       = (const int*)d_in[1];
    // d_in[2] edge_attr: unused (edge_dim=None). d_in[3] flag: unused.
    const float* W1       = (const float*)d_in[4];
    const float* att1_src = (const float*)d_in[5];
    const float* att1_dst = (const float*)d_in[6];
    const float* b1       = (const float*)d_in[7];
    const float* W3       = (const float*)d_in[8];
    const float* att3_src = (const float*)d_in[9];
    const float* att3_dst = (const float*)d_in[10];
    const float* b3       = (const float*)d_in[11];
    const float* mW1      = (const float*)d_in[12];
    const float* mb1      = (const float*)d_in[13];
    const float* mW2      = (const float*)d_in[14];
    const float* mb2      = (const float*)d_in[15];

    float* out_nodes = (float*)d_out;               // [N,32]
    float* out_edges = out_nodes + (size_t)NN * 32; // [E,2]

    // workspace layout (floats/ints) — ~115 MB
    float* ws = (float*)d_ws;
    float*    xl      = ws;                           // N*256 = 12.8M
    float*    h1      = ws + 12800000;                // N*64  = 3.2M
    float*    exbuf   = ws + 16000000;                // E*4   = 3.2M
    float*    alpha_p = ws + 19200000;                // E*4   = 3.2M (permuted alpha_n)
    float*    an2     = ws + 22400000;                // E*4   = 3.2M (orig-order L2 alpha_n)
    float*    a_s     = ws + 25600000;                // N*4
    float*    a_d     = ws + 25800000;                // N*4
    float*    den     = ws + 26000000;                // N*4
    unsigned* amax    = (unsigned*)(ws + 26200000);   // N*4
    int*      deg     = (int*)(ws + 26400000);        // N
    int*      cursor  = (int*)(ws + 26450000);        // N
    int*      rowptr  = (int*)(ws + 26500000);        // N+1
    int*      perm    = (int*)(ws + 26550008);        // E
    int*      psrc    = (int*)(ws + 27350008);        // E

    const int gemmRows = (NN + 63) / 64;  // 782
    const int EB = (EE + 255) / 256;      // 3125

    // ======== CSR build (shared by both layers) ========
    hipMemsetAsync(deg, 0, (size_t)NN * 4, stream);
    count_deg_k<<<EB, 256, 0, stream>>>(ei, deg);
    scan_k<<<1, 1024, 0, stream>>>(deg, rowptr, cursor);
    scatter_perm_k<<<EB, 256, 0, stream>>>(ei, cursor, perm, psrc);

    // ======== Layer 1 (C=64, HC=256) ========
    hipMemsetAsync(den,  0, (size_t)NN * NH * 4, stream);
    hipMemsetAsync(amax, 0, (size_t)NN * NH * 4, stream);

    gemm_tiled<<<dim3(gemmRows, 4), 256, 0, stream>>>(x, W1, xl, NN, INF, NH * 64);
    att_scores<64><<<(NN * NH * 64) / 256, 256, 0, stream>>>(xl, att1_src, att1_dst, a_s, a_d);
    edge_alpha<<<(EE * NH) / 256, 256, 0, stream>>>(ei, a_s, a_d, exbuf, amax);
    edge_expsum<<<(EE * NH) / 256, 256, 0, stream>>>(ei, exbuf, amax, den);
    normalize_perm<false><<<(EE * NH) / 256, 256, 0, stream>>>(perm, ei, exbuf, den, alpha_p, nullptr);
    aggregate_csr<64><<<NN, 256, 0, stream>>>(rowptr, psrc, alpha_p, xl, b1, h1);

    // ======== Layer 2 (C=32, HC=128) ========
    hipMemsetAsync(den,  0, (size_t)NN * NH * 4, stream);
    hipMemsetAsync(amax, 0, (size_t)NN * NH * 4, stream);

    gemm_tiled<<<dim3(gemmRows, 2), 256, 0, stream>>>(h1, W3, xl, NN, 64, NH * 32);
    att_scores<32><<<(NN * NH * 32) / 256, 256, 0, stream>>>(xl, att3_src, att3_dst, a_s, a_d);
    edge_alpha<<<(EE * NH) / 256, 256, 0, stream>>>(ei, a_s, a_d, exbuf, amax);
    edge_expsum<<<(EE * NH) / 256, 256, 0, stream>>>(ei, exbuf, amax, den);
    normalize_perm<true><<<(EE * NH) / 256, 256, 0, stream>>>(perm, ei, exbuf, den, alpha_p, an2);
    aggregate_csr<32><<<NN, 128, 0, stream>>>(rowptr, psrc, alpha_p, xl, b3, out_nodes);

    // ======== Edge MLP (tile-GEMM) ========
    edge_mlp_gemm<<<EE / TE, 128, 0, stream>>>(out_nodes, an2, ei, mW1, mb1, mW2, mb2, out_edges);
}

// Round 4
// 708.747 us; speedup vs baseline: 2.6875x; 1.1881x over previous
//
#include <hip/hip_runtime.h>

// Problem constants
constexpr int NN   = 50000;
constexpr int EE   = 800000;
constexpr int INF  = 128;   // input feat
constexpr int NH   = 4;     // heads

// ---------- Tiled fp32 GEMM: C[N,M] = A[N,K] @ B[K,M]; K%16==0, M%64==0 ----------
__global__ __launch_bounds__(256) void gemm_tiled(const float* __restrict__ A,
                                                  const float* __restrict__ B,
                                                  float* __restrict__ C,
                                                  int N, int K, int M) {
    __shared__ float As[16][68];   // [k][row], padded
    __shared__ float Bs[16][64];   // [k][col]
    const int tid = threadIdx.x;
    const int tx = tid & 15, ty = tid >> 4;
    const int row0 = blockIdx.x * 64, col0 = blockIdx.y * 64;

    float acc[4][4] = {};

    for (int k0 = 0; k0 < K; k0 += 16) {
        {
            const int a_row = tid >> 2;
            const int a_k   = (tid & 3) * 4;
            const int gr    = row0 + a_row;
            float4 v = make_float4(0.f, 0.f, 0.f, 0.f);
            if (gr < N) v = *(const float4*)(A + (size_t)gr * K + k0 + a_k);
            As[a_k + 0][a_row] = v.x;
            As[a_k + 1][a_row] = v.y;
            As[a_k + 2][a_row] = v.z;
            As[a_k + 3][a_row] = v.w;
        }
        {
            const int b_k = tid >> 4;
            const int b_c = (tid & 15) * 4;
            float4 w = *(const float4*)(B + (size_t)(k0 + b_k) * M + col0 + b_c);
            *(float4*)&Bs[b_k][b_c] = w;
        }
        __syncthreads();
        #pragma unroll
        for (int kk = 0; kk < 16; ++kk) {
            float4 a = *(const float4*)&As[kk][ty * 4];
            float4 b = *(const float4*)&Bs[kk][tx * 4];
            const float av[4] = {a.x, a.y, a.z, a.w};
            const float bv[4] = {b.x, b.y, b.z, b.w};
            #pragma unroll
            for (int i = 0; i < 4; ++i)
                #pragma unroll
                for (int j = 0; j < 4; ++j)
                    acc[i][j] = fmaf(av[i], bv[j], acc[i][j]);
        }
        __syncthreads();
    }
    #pragma unroll
    for (int i = 0; i < 4; ++i) {
        const int r = row0 + ty * 4 + i;
        if (r < N) {
            float* cp = C + (size_t)r * M + col0 + tx * 4;
            cp[0] = acc[i][0]; cp[1] = acc[i][1]; cp[2] = acc[i][2]; cp[3] = acc[i][3];
        }
    }
}

// ---------- CSR build ----------
__global__ __launch_bounds__(256) void count_deg_k(const int* __restrict__ ei,
                                                   int* __restrict__ deg) {
    const int e = blockIdx.x * 256 + threadIdx.x;
    if (e < EE) atomicAdd(&deg[ei[EE + e]], 1);
}

// single-block exclusive scan over deg[0..NN) -> rowptr[0..NN], cursor copy
__global__ __launch_bounds__(1024) void scan_k(const int* __restrict__ deg,
                                               int* __restrict__ rowptr,
                                               int* __restrict__ cursor) {
    __shared__ int wsum[16];
    const int tid = threadIdx.x;
    const int lane = tid & 63, wv = tid >> 6;
    int total = 0;
    for (int base = 0; base < NN; base += 1024) {
        const int i = base + tid;
        const int v = (i < NN) ? deg[i] : 0;
        int incl = v;
        #pragma unroll
        for (int d = 1; d < 64; d <<= 1) {
            int t = __shfl_up(incl, d, 64);
            if (lane >= d) incl += t;
        }
        if (lane == 63) wsum[wv] = incl;
        __syncthreads();
        if (wv == 0) {
            int s = (lane < 16) ? wsum[lane] : 0;
            #pragma unroll
            for (int d = 1; d < 16; d <<= 1) {
                int t = __shfl_up(s, d, 64);
                if (lane >= d) s += t;
            }
            if (lane < 16) wsum[lane] = s;
        }
        __syncthreads();
        const int excl = total + (wv > 0 ? wsum[wv - 1] : 0) + incl - v;
        const int chunk = wsum[15];
        if (i < NN) { rowptr[i] = excl; cursor[i] = excl; }
        total += chunk;
        __syncthreads();   // protect wsum before next iteration's writes
    }
    if (tid == 0) rowptr[NN] = total;
}

__global__ __launch_bounds__(256) void scatter_perm_k(const int* __restrict__ ei,
                                                      int* __restrict__ cursor,
                                                      int* __restrict__ perm,
                                                      int* __restrict__ psrc) {
    const int e = blockIdx.x * 256 + threadIdx.x;
    if (e >= EE) return;
    const int d = ei[EE + e];
    const int p = atomicAdd(&cursor[d], 1);
    perm[p] = e;
    psrc[p] = ei[e];
}

// ---------- attention scalars: a_s[p]=sum_c xl[p,c]*att_s[h,c] (p = n*H+h) ----------
template <int C>
__global__ __launch_bounds__(256) void att_scores(const float* __restrict__ xl,
                                                  const float* __restrict__ att_s,
                                                  const float* __restrict__ att_d,
                                                  float* __restrict__ a_s,
                                                  float* __restrict__ a_d) {
    const int idx = blockIdx.x * 256 + threadIdx.x;
    const int p = idx / C;   // n*H + h
    const int c = idx % C;
    if (p >= NN * NH) return;
    const int h = p & (NH - 1);
    const float v = xl[(size_t)p * C + c];
    float vs = v * att_s[h * C + c];
    float vd = v * att_d[h * C + c];
    #pragma unroll
    for (int m = C / 2; m; m >>= 1) {
        vs += __shfl_xor(vs, m, 64);
        vd += __shfl_xor(vd, m, 64);
    }
    if (c == 0) { a_s[p] = vs; a_d[p] = vd; }
}

// ---------- fused per-node edge softmax (CSR, one wave per dst node) ----------
// lane = jl*4 + h : 16 edges x 4 heads per iteration. Online softmax per lane,
// then merge across the 16 lanes sharing h (xor masks 4..32 preserve h=lane&3).
// Writes alpha_p in CSR order (contiguous); optionally orig-order via perm.
template <bool WRITE_ORIG>
__global__ __launch_bounds__(256) void softmax_csr(const int* __restrict__ rowptr,
                                                   const int* __restrict__ psrc,
                                                   const int* __restrict__ perm,
                                                   const float* __restrict__ a_s,
                                                   const float* __restrict__ a_d,
                                                   float* __restrict__ alpha_p,
                                                   float* __restrict__ alpha_orig) {
    const int wv = threadIdx.x >> 6, lane = threadIdx.x & 63;
    const int n = blockIdx.x * 4 + wv;
    if (n >= NN) return;
    const int h = lane & 3, jl = lane >> 2;
    const int r0 = rowptr[n], r1 = rowptr[n + 1];
    if (r0 == r1) return;   // empty segment: nothing referenced downstream
    const float ad = a_d[n * NH + h];

    float m = -1e30f, s = 0.f;
    for (int j0 = r0; j0 < r1; j0 += 16) {
        const int j = j0 + jl;
        if (j < r1) {
            const int sn = psrc[j];
            float a = a_s[sn * NH + h] + ad;
            a = (a > 0.f) ? a : 0.2f * a;
            const float mn = fmaxf(m, a);
            s = s * expf(m - mn) + expf(a - mn);
            m = mn;
        }
    }
    #pragma unroll
    for (int msk = 4; msk < 64; msk <<= 1) {
        const float mo = __shfl_xor(m, msk, 64);
        const float so = __shfl_xor(s, msk, 64);
        const float mn = fmaxf(m, mo);
        s = s * expf(m - mn) + so * expf(mo - mn);
        m = mn;
    }
    const float inv = 1.f / (s + 1e-16f);

    for (int j0 = r0; j0 < r1; j0 += 16) {
        const int j = j0 + jl;
        if (j < r1) {
            const int sn = psrc[j];
            float a = a_s[sn * NH + h] + ad;
            a = (a > 0.f) ? a : 0.2f * a;
            const float w = expf(a - m) * inv;
            alpha_p[j * NH + h] = w;
            if (WRITE_ORIG) alpha_orig[perm[j] * NH + h] = w;
        }
    }
}

// ---------- CSR aggregate + head-mean + bias: one block per dst node ----------
template <int C>   // per-head channels (64 for L1, 32 for L2)
__global__ __launch_bounds__(NH * C) void aggregate_csr(const int* __restrict__ rowptr,
                                                        const int* __restrict__ psrc,
                                                        const float* __restrict__ alpha_p,
                                                        const float* __restrict__ xl,
                                                        const float* __restrict__ bias,
                                                        float* __restrict__ out) {
    constexpr int HC = NH * C;
    __shared__ float red[HC];
    const int n = blockIdx.x;
    const int t = threadIdx.x;
    const int h = t / C;
    const int r0 = rowptr[n], r1 = rowptr[n + 1];
    float acc0 = 0.f, acc1 = 0.f;
    int j = r0;
    for (; j + 1 < r1; j += 2) {
        const int s0 = psrc[j];
        const int s1 = psrc[j + 1];
        const float w0 = alpha_p[j * NH + h];
        const float w1 = alpha_p[(j + 1) * NH + h];
        acc0 = fmaf(w0, xl[(size_t)s0 * HC + t], acc0);
        acc1 = fmaf(w1, xl[(size_t)s1 * HC + t], acc1);
    }
    if (j < r1) {
        const int s0 = psrc[j];
        const float w0 = alpha_p[j * NH + h];
        acc0 = fmaf(w0, xl[(size_t)s0 * HC + t], acc0);
    }
    red[t] = acc0 + acc1;
    __syncthreads();
    if (t < C) {
        out[(size_t)n * C + t] =
            (red[t] + red[t + C] + red[t + 2 * C] + red[t + 3 * C]) * 0.25f + bias[t];
    }
}

// ---------- edge MLP as tile-GEMM ----------
constexpr int TE = 128;          // edges per block
constexpr int FPAD = 4;          // Fs row pad (row stride 132 floats)
__global__ __launch_bounds__(128) void edge_mlp_gemm(const float* __restrict__ nodes,  // [N,32]
                                                     const float* __restrict__ alpha,  // [E,4]
                                                     const int* __restrict__ ei,
                                                     const float* __restrict__ mW1,    // [68,64]
                                                     const float* __restrict__ mb1,    // [64]
                                                     const float* __restrict__ mW2,    // [64,2]
                                                     const float* __restrict__ mb2,    // [2]
                                                     float* __restrict__ out) {        // [E,2]
    __shared__ float W1s[68 * 64];           // 17.4 KB
    __shared__ float Fs[34][TE + FPAD];      // 17.95 KB, k-major chunk

    const int tid = threadIdx.x;
    const int tx = tid & 7;      // hid group: hid = tx*8 + j
    const int ty = tid >> 3;     // edge group
    const int e0 = blockIdx.x * TE;
    const int e  = e0 + tid;     // gather edge for this thread

    for (int i = tid * 4; i < 68 * 64; i += 128 * 4)
        *(float4*)&W1s[i] = *(const float4*)&mW1[i];

    float w2r[8][2], b1r[8];
    #pragma unroll
    for (int j = 0; j < 8; ++j) {
        w2r[j][0] = mW2[(tx * 8 + j) * 2 + 0];
        w2r[j][1] = mW2[(tx * 8 + j) * 2 + 1];
        b1r[j]    = mb1[tx * 8 + j];
    }
    const float bo0 = mb2[0], bo1 = mb2[1];

    const int src = ei[e];
    const int dst = ei[EE + e];

    float acc[8][8] = {};

    // ---- chunk 0: k = 0..33  (src feats 0..31, alpha 0..1) ----
    {
        const float4* srow = (const float4*)(nodes + (size_t)src * 32);
        float4 v[8];
        #pragma unroll
        for (int q = 0; q < 8; ++q) v[q] = srow[q];
        const float2 al = *(const float2*)&alpha[(size_t)e * 4];
        #pragma unroll
        for (int q = 0; q < 8; ++q) {
            Fs[q * 4 + 0][tid] = v[q].x;
            Fs[q * 4 + 1][tid] = v[q].y;
            Fs[q * 4 + 2][tid] = v[q].z;
            Fs[q * 4 + 3][tid] = v[q].w;
        }
        Fs[32][tid] = al.x;
        Fs[33][tid] = al.y;
    }
    __syncthreads();
    #pragma unroll 2
    for (int k = 0; k < 34; ++k) {
        const float4 a0 = *(const float4*)&Fs[k][ty * 8];
        const float4 a1 = *(const float4*)&Fs[k][ty * 8 + 4];
        const float4 b0 = *(const float4*)&W1s[k * 64 + tx * 8];
        const float4 b1 = *(const float4*)&W1s[k * 64 + tx * 8 + 4];
        const float av[8] = {a0.x, a0.y, a0.z, a0.w, a1.x, a1.y, a1.z, a1.w};
        const float bv[8] = {b0.x, b0.y, b0.z, b0.w, b1.x, b1.y, b1.z, b1.w};
        #pragma unroll
        for (int i = 0; i < 8; ++i)
            #pragma unroll
            for (int j = 0; j < 8; ++j)
                acc[i][j] = fmaf(av[i], bv[j], acc[i][j]);
    }
    __syncthreads();

    // ---- chunk 1: k = 34..67  (alpha 2..3, dst feats 0..31) ----
    {
        const float4* drow = (const float4*)(nodes + (size_t)dst * 32);
        float4 v[8];
        #pragma unroll
        for (int q = 0; q < 8; ++q) v[q] = drow[q];
        const float2 al = *(const float2*)&alpha[(size_t)e * 4 + 2];
        Fs[0][tid] = al.x;
        Fs[1][tid] = al.y;
        #pragma unroll
        for (int q = 0; q < 8; ++q) {
            Fs[2 + q * 4 + 0][tid] = v[q].x;
            Fs[2 + q * 4 + 1][tid] = v[q].y;
            Fs[2 + q * 4 + 2][tid] = v[q].z;
            Fs[2 + q * 4 + 3][tid] = v[q].w;
        }
    }
    __syncthreads();
    #pragma unroll 2
    for (int k = 0; k < 34; ++k) {
        const float4 a0 = *(const float4*)&Fs[k][ty * 8];
        const float4 a1 = *(const float4*)&Fs[k][ty * 8 + 4];
        const float4 b0 = *(const float4*)&W1s[(34 + k) * 64 + tx * 8];
        const float4 b1 = *(const float4*)&W1s[(34 + k) * 64 + tx * 8 + 4];
        const float av[8] = {a0.x, a0.y, a0.z, a0.w, a1.x, a1.y, a1.z, a1.w};
        const float bv[8] = {b0.x, b0.y, b0.z, b0.w, b1.x, b1.y, b1.z, b1.w};
        #pragma unroll
        for (int i = 0; i < 8; ++i)
            #pragma unroll
            for (int j = 0; j < 8; ++j)
                acc[i][j] = fmaf(av[i], bv[j], acc[i][j]);
    }

    // ---- epilogue: relu + b1, layer-2 dot, reduce across tx (8 lanes), store ----
    #pragma unroll
    for (int i = 0; i < 8; ++i) {
        float v0 = 0.f, v1 = 0.f;
        #pragma unroll
        for (int j = 0; j < 8; ++j) {
            const float hv = fmaxf(acc[i][j] + b1r[j], 0.f);
            v0 = fmaf(hv, w2r[j][0], v0);
            v1 = fmaf(hv, w2r[j][1], v1);
        }
        v0 += __shfl_xor(v0, 1, 64); v0 += __shfl_xor(v0, 2, 64); v0 += __shfl_xor(v0, 4, 64);
        v1 += __shfl_xor(v1, 1, 64); v1 += __shfl_xor(v1, 2, 64); v1 += __shfl_xor(v1, 4, 64);
        if (tx == 0) {
            *(float2*)&out[(size_t)(e0 + ty * 8 + i) * 2] = make_float2(v0 + bo0, v1 + bo1);
        }
    }
}

extern "C" void kernel_launch(void* const* d_in, const int* in_sizes, int n_in,
                              void* d_out, int out_size, void* d_ws, size_t ws_size,
                              hipStream_t stream) {
    const float* x        = (const float*)d_in[0];
    const int*   ei       = (const int*)d_in[1];
    // d_in[2] edge_attr: unused (edge_dim=None). d_in[3] flag: unused.
    const float* W1       = (const float*)d_in[4];
    const float* att1_src = (const float*)d_in[5];
    const float* att1_dst = (const float*)d_in[6];
    const float* b1       = (const float*)d_in[7];
    const float* W3       = (const float*)d_in[8];
    const float* att3_src = (const float*)d_in[9];
    const float* att3_dst = (const float*)d_in[10];
    const float* b3       = (const float*)d_in[11];
    const float* mW1      = (const float*)d_in[12];
    const float* mb1      = (const float*)d_in[13];
    const float* mW2      = (const float*)d_in[14];
    const float* mb2      = (const float*)d_in[15];

    float* out_nodes = (float*)d_out;               // [N,32]
    float* out_edges = out_nodes + (size_t)NN * 32; // [E,2]

    // workspace layout (floats/ints)
    float* ws = (float*)d_ws;
    float*    xl      = ws;                           // N*256 = 12.8M
    float*    h1      = ws + 12800000;                // N*64
    float*    alpha_p = ws + 19200000;                // E*4 (CSR-order alpha_n)
    float*    an2     = ws + 22400000;                // E*4 (orig-order L2 alpha_n)
    float*    a_s     = ws + 25600000;                // N*4
    float*    a_d     = ws + 25800000;                // N*4
    int*      deg     = (int*)(ws + 26400000);        // N
    int*      cursor  = (int*)(ws + 26450000);        // N
    int*      rowptr  = (int*)(ws + 26500000);        // N+1
    int*      perm    = (int*)(ws + 26550008);        // E
    int*      psrc    = (int*)(ws + 27350008);        // E

    const int gemmRows = (NN + 63) / 64;  // 782
    const int EB = (EE + 255) / 256;      // 3125
    const int SB = (NN + 3) / 4;          // softmax blocks (4 waves/block)

    // ======== CSR build (shared by both layers) ========
    hipMemsetAsync(deg, 0, (size_t)NN * 4, stream);
    count_deg_k<<<EB, 256, 0, stream>>>(ei, deg);
    scan_k<<<1, 1024, 0, stream>>>(deg, rowptr, cursor);
    scatter_perm_k<<<EB, 256, 0, stream>>>(ei, cursor, perm, psrc);

    // ======== Layer 1 (C=64, HC=256) ========
    gemm_tiled<<<dim3(gemmRows, 4), 256, 0, stream>>>(x, W1, xl, NN, INF, NH * 64);
    att_scores<64><<<(NN * NH * 64) / 256, 256, 0, stream>>>(xl, att1_src, att1_dst, a_s, a_d);
    softmax_csr<false><<<SB, 256, 0, stream>>>(rowptr, psrc, perm, a_s, a_d, alpha_p, nullptr);
    aggregate_csr<64><<<NN, 256, 0, stream>>>(rowptr, psrc, alpha_p, xl, b1, h1);

    // ======== Layer 2 (C=32, HC=128) ========
    gemm_tiled<<<dim3(gemmRows, 2), 256, 0, stream>>>(h1, W3, xl, NN, 64, NH * 32);
    att_scores<32><<<(NN * NH * 32) / 256, 256, 0, stream>>>(xl, att3_src, att3_dst, a_s, a_d);
    softmax_csr<true><<<SB, 256, 0, stream>>>(rowptr, psrc, perm, a_s, a_d, alpha_p, an2);
    aggregate_csr<32><<<NN, 128, 0, stream>>>(rowptr, psrc, alpha_p, xl, b3, out_nodes);

    // ======== Edge MLP (tile-GEMM) ========
    edge_mlp_gemm<<<EE / TE, 128, 0, stream>>>(out_nodes, an2, ei, mW1, mb1, mW2, mb2, out_edges);
}

// Round 5
// 621.144 us; speedup vs baseline: 3.0666x; 1.1410x over previous
//
#include <hip/hip_runtime.h>

// Problem constants
constexpr int NN   = 50000;
constexpr int EE   = 800000;
constexpr int INF  = 128;   // input feat
constexpr int NH   = 4;     // heads

// ---------- Tiled fp32 GEMM with fused attention-score epilogue ----------
// C[N,M] = A[N,K] @ B[K,M]; K%16==0, M%64==0, col-tile 64 aligns to head width CH.
// a_s[n*4+h] = sum_c C[n, h*CH+c]*att_s[h*CH+c]  (same for a_d) computed from acc.
template <int CH>
__global__ __launch_bounds__(256) void gemm_att(const float* __restrict__ A,
                                                const float* __restrict__ B,
                                                float* __restrict__ C,
                                                const float* __restrict__ att_s,
                                                const float* __restrict__ att_d,
                                                float* __restrict__ a_s,
                                                float* __restrict__ a_d,
                                                int N, int K, int M) {
    __shared__ float As[16][68];   // [k][row], padded
    __shared__ float Bs[16][64];   // [k][col]
    const int tid = threadIdx.x;
    const int tx = tid & 15, ty = tid >> 4;
    const int row0 = blockIdx.x * 64, col0 = blockIdx.y * 64;

    // per-thread att fragment (col = col0 + tx*4 + j)
    const int col  = col0 + tx * 4;
    const int head = col / CH;
    const int pos  = col % CH;
    float attS[4], attD[4];
    #pragma unroll
    for (int j = 0; j < 4; ++j) {
        attS[j] = att_s[head * CH + pos + j];
        attD[j] = att_d[head * CH + pos + j];
    }

    float acc[4][4] = {};

    for (int k0 = 0; k0 < K; k0 += 16) {
        {
            const int a_row = tid >> 2;
            const int a_k   = (tid & 3) * 4;
            const int gr    = row0 + a_row;
            float4 v = make_float4(0.f, 0.f, 0.f, 0.f);
            if (gr < N) v = *(const float4*)(A + (size_t)gr * K + k0 + a_k);
            As[a_k + 0][a_row] = v.x;
            As[a_k + 1][a_row] = v.y;
            As[a_k + 2][a_row] = v.z;
            As[a_k + 3][a_row] = v.w;
        }
        {
            const int b_k = tid >> 4;
            const int b_c = (tid & 15) * 4;
            float4 w = *(const float4*)(B + (size_t)(k0 + b_k) * M + col0 + b_c);
            *(float4*)&Bs[b_k][b_c] = w;
        }
        __syncthreads();
        #pragma unroll
        for (int kk = 0; kk < 16; ++kk) {
            float4 a = *(const float4*)&As[kk][ty * 4];
            float4 b = *(const float4*)&Bs[kk][tx * 4];
            const float av[4] = {a.x, a.y, a.z, a.w};
            const float bv[4] = {b.x, b.y, b.z, b.w};
            #pragma unroll
            for (int i = 0; i < 4; ++i)
                #pragma unroll
                for (int j = 0; j < 4; ++j)
                    acc[i][j] = fmaf(av[i], bv[j], acc[i][j]);
        }
        __syncthreads();
    }
    #pragma unroll
    for (int i = 0; i < 4; ++i) {
        const int r = row0 + ty * 4 + i;
        if (r < N) {
            float* cp = C + (size_t)r * M + col0 + tx * 4;
            cp[0] = acc[i][0]; cp[1] = acc[i][1]; cp[2] = acc[i][2]; cp[3] = acc[i][3];
        }
        // fused att epilogue for this row
        float ss = 0.f, sd = 0.f;
        #pragma unroll
        for (int j = 0; j < 4; ++j) {
            ss = fmaf(acc[i][j], attS[j], ss);
            sd = fmaf(acc[i][j], attD[j], sd);
        }
        #pragma unroll
        for (int msk = 1; msk < CH / 4; msk <<= 1) {
            ss += __shfl_xor(ss, msk, 64);
            sd += __shfl_xor(sd, msk, 64);
        }
        if ((tx & (CH / 4 - 1)) == 0 && r < N) {
            a_s[r * NH + head] = ss;
            a_d[r * NH + head] = sd;
        }
    }
}

// ---------- CSR build ----------
__global__ __launch_bounds__(256) void count_deg_k(const int* __restrict__ ei,
                                                   int* __restrict__ deg) {
    const int e = blockIdx.x * 256 + threadIdx.x;
    if (e < EE) atomicAdd(&deg[ei[EE + e]], 1);
}

// single-block exclusive scan over deg[0..NN) -> rowptr[0..NN], cursor copy
__global__ __launch_bounds__(1024) void scan_k(const int* __restrict__ deg,
                                               int* __restrict__ rowptr,
                                               int* __restrict__ cursor) {
    __shared__ int wsum[16];
    const int tid = threadIdx.x;
    const int lane = tid & 63, wv = tid >> 6;
    int total = 0;
    for (int base = 0; base < NN; base += 1024) {
        const int i = base + tid;
        const int v = (i < NN) ? deg[i] : 0;
        int incl = v;
        #pragma unroll
        for (int d = 1; d < 64; d <<= 1) {
            int t = __shfl_up(incl, d, 64);
            if (lane >= d) incl += t;
        }
        if (lane == 63) wsum[wv] = incl;
        __syncthreads();
        if (wv == 0) {
            int s = (lane < 16) ? wsum[lane] : 0;
            #pragma unroll
            for (int d = 1; d < 16; d <<= 1) {
                int t = __shfl_up(s, d, 64);
                if (lane >= d) s += t;
            }
            if (lane < 16) wsum[lane] = s;
        }
        __syncthreads();
        const int excl = total + (wv > 0 ? wsum[wv - 1] : 0) + incl - v;
        const int chunk = wsum[15];
        if (i < NN) { rowptr[i] = excl; cursor[i] = excl; }
        total += chunk;
        __syncthreads();   // protect wsum before next iteration's writes
    }
    if (tid == 0) rowptr[NN] = total;
}

__global__ __launch_bounds__(256) void scatter_perm_k(const int* __restrict__ ei,
                                                      int* __restrict__ cursor,
                                                      int* __restrict__ perm,
                                                      int* __restrict__ psrc) {
    const int e = blockIdx.x * 256 + threadIdx.x;
    if (e >= EE) return;
    const int d = ei[EE + e];
    const int p = atomicAdd(&cursor[d], 1);
    perm[p] = e;
    psrc[p] = ei[e];
}

// ---------- fused per-node edge softmax (CSR, one wave per dst node) ----------
// lane = jl*4 + h. Pass 1: compute scores, store to alpha_p, online m/s.
// Merge across 16 lanes sharing h. Pass 2: re-read stored scores (contiguous),
// write normalized weights; optionally orig-order via perm.
template <bool WRITE_ORIG>
__global__ __launch_bounds__(256) void softmax_csr(const int* __restrict__ rowptr,
                                                   const int* __restrict__ psrc,
                                                   const int* __restrict__ perm,
                                                   const float* __restrict__ a_s,
                                                   const float* __restrict__ a_d,
                                                   float* __restrict__ alpha_p,
                                                   float* __restrict__ alpha_orig) {
    const int wv = threadIdx.x >> 6, lane = threadIdx.x & 63;
    const int n = blockIdx.x * 4 + wv;
    if (n >= NN) return;
    const int h = lane & 3, jl = lane >> 2;
    const int r0 = rowptr[n], r1 = rowptr[n + 1];
    if (r0 == r1) return;   // empty segment: nothing referenced downstream
    const float ad = a_d[n * NH + h];

    float m = -1e30f, s = 0.f;
    for (int j0 = r0; j0 < r1; j0 += 16) {
        const int j = j0 + jl;
        if (j < r1) {
            const int sn = psrc[j];
            float a = a_s[sn * NH + h] + ad;
            a = (a > 0.f) ? a : 0.2f * a;
            alpha_p[j * NH + h] = a;          // stash score
            const float mn = fmaxf(m, a);
            s = s * expf(m - mn) + expf(a - mn);
            m = mn;
        }
    }
    #pragma unroll
    for (int msk = 4; msk < 64; msk <<= 1) {
        const float mo = __shfl_xor(m, msk, 64);
        const float so = __shfl_xor(s, msk, 64);
        const float mn = fmaxf(m, mo);
        s = s * expf(m - mn) + so * expf(mo - mn);
        m = mn;
    }
    const float inv = 1.f / (s + 1e-16f);

    for (int j0 = r0; j0 < r1; j0 += 16) {
        const int j = j0 + jl;
        if (j < r1) {
            const float a = alpha_p[j * NH + h];
            const float w = expf(a - m) * inv;
            alpha_p[j * NH + h] = w;
            if (WRITE_ORIG) alpha_orig[perm[j] * NH + h] = w;
        }
    }
}

// ---------- wave-per-node CSR aggregate + head-mean + bias, HC=256 (L1) ----------
// Lane holds float4 = channels 4*lane..4*lane+3; head = lane>>4. Unroll 4 edges.
__global__ __launch_bounds__(256) void aggregate_w256(const int* __restrict__ rowptr,
                                                      const int* __restrict__ psrc,
                                                      const float* __restrict__ alpha_p,
                                                      const float* __restrict__ xl,
                                                      const float* __restrict__ bias,
                                                      float* __restrict__ out) {
    const int wv = threadIdx.x >> 6, lane = threadIdx.x & 63;
    const int n = blockIdx.x * 4 + wv;
    if (n >= NN) return;
    const int hh = lane >> 4;
    const int r0 = rowptr[n], r1 = rowptr[n + 1];
    const float4* X4 = (const float4*)xl;   // row stride 64 float4

    float4 A0 = {0,0,0,0}, A1 = {0,0,0,0}, A2 = {0,0,0,0}, A3 = {0,0,0,0};
    int j = r0;
    for (; j + 3 < r1; j += 4) {
        const int s0 = psrc[j], s1 = psrc[j+1], s2 = psrc[j+2], s3 = psrc[j+3];
        const float w0 = alpha_p[j*NH + hh],     w1 = alpha_p[(j+1)*NH + hh];
        const float w2 = alpha_p[(j+2)*NH + hh], w3 = alpha_p[(j+3)*NH + hh];
        const float4 v0 = X4[(size_t)s0*64 + lane];
        const float4 v1 = X4[(size_t)s1*64 + lane];
        const float4 v2 = X4[(size_t)s2*64 + lane];
        const float4 v3 = X4[(size_t)s3*64 + lane];
        A0.x = fmaf(w0, v0.x, A0.x); A0.y = fmaf(w0, v0.y, A0.y);
        A0.z = fmaf(w0, v0.z, A0.z); A0.w = fmaf(w0, v0.w, A0.w);
        A1.x = fmaf(w1, v1.x, A1.x); A1.y = fmaf(w1, v1.y, A1.y);
        A1.z = fmaf(w1, v1.z, A1.z); A1.w = fmaf(w1, v1.w, A1.w);
        A2.x = fmaf(w2, v2.x, A2.x); A2.y = fmaf(w2, v2.y, A2.y);
        A2.z = fmaf(w2, v2.z, A2.z); A2.w = fmaf(w2, v2.w, A2.w);
        A3.x = fmaf(w3, v3.x, A3.x); A3.y = fmaf(w3, v3.y, A3.y);
        A3.z = fmaf(w3, v3.z, A3.z); A3.w = fmaf(w3, v3.w, A3.w);
    }
    for (; j < r1; ++j) {
        const int s0 = psrc[j];
        const float w0 = alpha_p[j*NH + hh];
        const float4 v0 = X4[(size_t)s0*64 + lane];
        A0.x = fmaf(w0, v0.x, A0.x); A0.y = fmaf(w0, v0.y, A0.y);
        A0.z = fmaf(w0, v0.z, A0.z); A0.w = fmaf(w0, v0.w, A0.w);
    }
    float4 t;
    t.x = (A0.x + A1.x) + (A2.x + A3.x);
    t.y = (A0.y + A1.y) + (A2.y + A3.y);
    t.z = (A0.z + A1.z) + (A2.z + A3.z);
    t.w = (A0.w + A1.w) + (A2.w + A3.w);
    // head-mean: lanes l, l^16, l^32, l^48 hold same channel-within-head
    #pragma unroll
    for (int msk = 16; msk < 64; msk <<= 1) {
        t.x += __shfl_xor(t.x, msk, 64);
        t.y += __shfl_xor(t.y, msk, 64);
        t.z += __shfl_xor(t.z, msk, 64);
        t.w += __shfl_xor(t.w, msk, 64);
    }
    if (lane < 16) {
        const float4 b = ((const float4*)bias)[lane];
        float4 o;
        o.x = t.x * 0.25f + b.x; o.y = t.y * 0.25f + b.y;
        o.z = t.z * 0.25f + b.z; o.w = t.w * 0.25f + b.w;
        ((float4*)out)[(size_t)n * 16 + lane] = o;
    }
}

// ---------- wave-per-node CSR aggregate, HC=128 (L2): half-wave per edge ----------
__global__ __launch_bounds__(256) void aggregate_w128(const int* __restrict__ rowptr,
                                                      const int* __restrict__ psrc,
                                                      const float* __restrict__ alpha_p,
                                                      const float* __restrict__ xl,
                                                      const float* __restrict__ bias,
                                                      float* __restrict__ out) {
    const int wv = threadIdx.x >> 6, lane = threadIdx.x & 63;
    const int n = blockIdx.x * 4 + wv;
    if (n >= NN) return;
    const int cl = lane & 31, half = lane >> 5;
    const int hh = cl >> 3;                 // head = (cl*4)/32
    const int r0 = rowptr[n], r1 = rowptr[n + 1];
    const float4* X4 = (const float4*)xl;   // row stride 32 float4

    float4 A0 = {0,0,0,0}, A1 = {0,0,0,0};
    int jb = r0;
    for (; jb + 3 < r1; jb += 4) {
        const int ja = jb + half, jc = jb + 2 + half;
        const int sa = psrc[ja], sc = psrc[jc];
        const float wa = alpha_p[ja*NH + hh], wc = alpha_p[jc*NH + hh];
        const float4 va = X4[(size_t)sa*32 + cl];
        const float4 vc = X4[(size_t)sc*32 + cl];
        A0.x = fmaf(wa, va.x, A0.x); A0.y = fmaf(wa, va.y, A0.y);
        A0.z = fmaf(wa, va.z, A0.z); A0.w = fmaf(wa, va.w, A0.w);
        A1.x = fmaf(wc, vc.x, A1.x); A1.y = fmaf(wc, vc.y, A1.y);
        A1.z = fmaf(wc, vc.z, A1.z); A1.w = fmaf(wc, vc.w, A1.w);
    }
    for (; jb < r1; jb += 2) {
        const int ja = jb + half;
        const bool valid = ja < r1;
        const int sa = psrc[valid ? ja : r0];
        const float wa = valid ? alpha_p[ja*NH + hh] : 0.f;
        const float4 va = X4[(size_t)sa*32 + cl];
        A0.x = fmaf(wa, va.x, A0.x); A0.y = fmaf(wa, va.y, A0.y);
        A0.z = fmaf(wa, va.z, A0.z); A0.w = fmaf(wa, va.w, A0.w);
    }
    float4 t;
    t.x = A0.x + A1.x; t.y = A0.y + A1.y; t.z = A0.z + A1.z; t.w = A0.w + A1.w;
    // combine halves (xor 32), then head-mean (xor 8, 16 over cl)
    #pragma unroll
    for (int q = 0; q < 3; ++q) {
        const int msk = (q == 0) ? 32 : (q == 1) ? 8 : 16;
        t.x += __shfl_xor(t.x, msk, 64);
        t.y += __shfl_xor(t.y, msk, 64);
        t.z += __shfl_xor(t.z, msk, 64);
        t.w += __shfl_xor(t.w, msk, 64);
    }
    if (lane < 8) {
        const float4 b = ((const float4*)bias)[lane];
        float4 o;
        o.x = t.x * 0.25f + b.x; o.y = t.y * 0.25f + b.y;
        o.z = t.z * 0.25f + b.z; o.w = t.w * 0.25f + b.w;
        ((float4*)out)[(size_t)n * 8 + lane] = o;
    }
}

// ---------- edge MLP as tile-GEMM ----------
constexpr int TE = 128;          // edges per block
constexpr int FPAD = 4;          // Fs row pad (row stride 132 floats)
__global__ __launch_bounds__(128) void edge_mlp_gemm(const float* __restrict__ nodes,  // [N,32]
                                                     const float* __restrict__ alpha,  // [E,4]
                                                     const int* __restrict__ ei,
                                                     const float* __restrict__ mW1,    // [68,64]
                                                     const float* __restrict__ mb1,    // [64]
                                                     const float* __restrict__ mW2,    // [64,2]
                                                     const float* __restrict__ mb2,    // [2]
                                                     float* __restrict__ out) {        // [E,2]
    __shared__ float W1s[68 * 64];           // 17.4 KB
    __shared__ float Fs[34][TE + FPAD];      // 17.95 KB, k-major chunk

    const int tid = threadIdx.x;
    const int tx = tid & 7;      // hid group: hid = tx*8 + j
    const int ty = tid >> 3;     // edge group
    const int e0 = blockIdx.x * TE;
    const int e  = e0 + tid;     // gather edge for this thread

    for (int i = tid * 4; i < 68 * 64; i += 128 * 4)
        *(float4*)&W1s[i] = *(const float4*)&mW1[i];

    float w2r[8][2], b1r[8];
    #pragma unroll
    for (int j = 0; j < 8; ++j) {
        w2r[j][0] = mW2[(tx * 8 + j) * 2 + 0];
        w2r[j][1] = mW2[(tx * 8 + j) * 2 + 1];
        b1r[j]    = mb1[tx * 8 + j];
    }
    const float bo0 = mb2[0], bo1 = mb2[1];

    const int src = ei[e];
    const int dst = ei[EE + e];

    float acc[8][8] = {};

    // ---- chunk 0: k = 0..33  (src feats 0..31, alpha 0..1) ----
    {
        const float4* srow = (const float4*)(nodes + (size_t)src * 32);
        float4 v[8];
        #pragma unroll
        for (int q = 0; q < 8; ++q) v[q] = srow[q];
        const float2 al = *(const float2*)&alpha[(size_t)e * 4];
        #pragma unroll
        for (int q = 0; q < 8; ++q) {
            Fs[q * 4 + 0][tid] = v[q].x;
            Fs[q * 4 + 1][tid] = v[q].y;
            Fs[q * 4 + 2][tid] = v[q].z;
            Fs[q * 4 + 3][tid] = v[q].w;
        }
        Fs[32][tid] = al.x;
        Fs[33][tid] = al.y;
    }
    __syncthreads();
    #pragma unroll 2
    for (int k = 0; k < 34; ++k) {
        const float4 a0 = *(const float4*)&Fs[k][ty * 8];
        const float4 a1 = *(const float4*)&Fs[k][ty * 8 + 4];
        const float4 b0 = *(const float4*)&W1s[k * 64 + tx * 8];
        const float4 b1 = *(const float4*)&W1s[k * 64 + tx * 8 + 4];
        const float av[8] = {a0.x, a0.y, a0.z, a0.w, a1.x, a1.y, a1.z, a1.w};
        const float bv[8] = {b0.x, b0.y, b0.z, b0.w, b1.x, b1.y, b1.z, b1.w};
        #pragma unroll
        for (int i = 0; i < 8; ++i)
            #pragma unroll
            for (int j = 0; j < 8; ++j)
                acc[i][j] = fmaf(av[i], bv[j], acc[i][j]);
    }
    __syncthreads();

    // ---- chunk 1: k = 34..67  (alpha 2..3, dst feats 0..31) ----
    {
        const float4* drow = (const float4*)(nodes + (size_t)dst * 32);
        float4 v[8];
        #pragma unroll
        for (int q = 0; q < 8; ++q) v[q] = drow[q];
        const float2 al = *(const float2*)&alpha[(size_t)e * 4 + 2];
        Fs[0][tid] = al.x;
        Fs[1][tid] = al.y;
        #pragma unroll
        for (int q = 0; q < 8; ++q) {
            Fs[2 + q * 4 + 0][tid] = v[q].x;
            Fs[2 + q * 4 + 1][tid] = v[q].y;
            Fs[2 + q * 4 + 2][tid] = v[q].z;
            Fs[2 + q * 4 + 3][tid] = v[q].w;
        }
    }
    __syncthreads();
    #pragma unroll 2
    for (int k = 0; k < 34; ++k) {
        const float4 a0 = *(const float4*)&Fs[k][ty * 8];
        const float4 a1 = *(const float4*)&Fs[k][ty * 8 + 4];
        const float4 b0 = *(const float4*)&W1s[(34 + k) * 64 + tx * 8];
        const float4 b1 = *(const float4*)&W1s[(34 + k) * 64 + tx * 8 + 4];
        const float av[8] = {a0.x, a0.y, a0.z, a0.w, a1.x, a1.y, a1.z, a1.w};
        const float bv[8] = {b0.x, b0.y, b0.z, b0.w, b1.x, b1.y, b1.z, b1.w};
        #pragma unroll
        for (int i = 0; i < 8; ++i)
            #pragma unroll
            for (int j = 0; j < 8; ++j)
                acc[i][j] = fmaf(av[i], bv[j], acc[i][j]);
    }

    // ---- epilogue: relu + b1, layer-2 dot, reduce across tx (8 lanes), store ----
    #pragma unroll
    for (int i = 0; i < 8; ++i) {
        float v0 = 0.f, v1 = 0.f;
        #pragma unroll
        for (int j = 0; j < 8; ++j) {
            const float hv = fmaxf(acc[i][j] + b1r[j], 0.f);
            v0 = fmaf(hv, w2r[j][0], v0);
            v1 = fmaf(hv, w2r[j][1], v1);
        }
        v0 += __shfl_xor(v0, 1, 64); v0 += __shfl_xor(v0, 2, 64); v0 += __shfl_xor(v0, 4, 64);
        v1 += __shfl_xor(v1, 1, 64); v1 += __shfl_xor(v1, 2, 64); v1 += __shfl_xor(v1, 4, 64);
        if (tx == 0) {
            *(float2*)&out[(size_t)(e0 + ty * 8 + i) * 2] = make_float2(v0 + bo0, v1 + bo1);
        }
    }
}

extern "C" void kernel_launch(void* const* d_in, const int* in_sizes, int n_in,
                              void* d_out, int out_size, void* d_ws, size_t ws_size,
                              hipStream_t stream) {
    const float* x        = (const float*)d_in[0];
    const int*   ei       = (const int*)d_in[1];
    // d_in[2] edge_attr: unused (edge_dim=None). d_in[3] flag: unused.
    const float* W1       = (const float*)d_in[4];
    const float* att1_src = (const float*)d_in[5];
    const float* att1_dst = (const float*)d_in[6];
    const float* b1       = (const float*)d_in[7];
    const float* W3       = (const float*)d_in[8];
    const float* att3_src = (const float*)d_in[9];
    const float* att3_dst = (const float*)d_in[10];
    const float* b3       = (const float*)d_in[11];
    const float* mW1      = (const float*)d_in[12];
    const float* mb1      = (const float*)d_in[13];
    const float* mW2      = (const float*)d_in[14];
    const float* mb2      = (const float*)d_in[15];

    float* out_nodes = (float*)d_out;               // [N,32]
    float* out_edges = out_nodes + (size_t)NN * 32; // [E,2]

    // workspace layout (floats/ints)
    float* ws = (float*)d_ws;
    float*    xl      = ws;                           // N*256 = 12.8M
    float*    h1      = ws + 12800000;                // N*64
    float*    alpha_p = ws + 19200000;                // E*4 (CSR-order scores->alpha_n)
    float*    an2     = ws + 22400000;                // E*4 (orig-order L2 alpha_n)
    float*    a_s     = ws + 25600000;                // N*4
    float*    a_d     = ws + 25800000;                // N*4
    int*      deg     = (int*)(ws + 26400000);        // N
    int*      cursor  = (int*)(ws + 26450000);        // N
    int*      rowptr  = (int*)(ws + 26500000);        // N+1
    int*      perm    = (int*)(ws + 26550008);        // E
    int*      psrc    = (int*)(ws + 27350008);        // E

    const int gemmRows = (NN + 63) / 64;  // 782
    const int EB = (EE + 255) / 256;      // 3125
    const int NB4 = (NN + 3) / 4;         // wave-per-node blocks (4 waves/block)

    // ======== CSR build (shared by both layers) ========
    hipMemsetAsync(deg, 0, (size_t)NN * 4, stream);
    count_deg_k<<<EB, 256, 0, stream>>>(ei, deg);
    scan_k<<<1, 1024, 0, stream>>>(deg, rowptr, cursor);
    scatter_perm_k<<<EB, 256, 0, stream>>>(ei, cursor, perm, psrc);

    // ======== Layer 1 (C=64, HC=256) ========
    gemm_att<64><<<dim3(gemmRows, 4), 256, 0, stream>>>(x, W1, xl, att1_src, att1_dst,
                                                        a_s, a_d, NN, INF, NH * 64);
    softmax_csr<false><<<NB4, 256, 0, stream>>>(rowptr, psrc, perm, a_s, a_d, alpha_p, nullptr);
    aggregate_w256<<<NB4, 256, 0, stream>>>(rowptr, psrc, alpha_p, xl, b1, h1);

    // ======== Layer 2 (C=32, HC=128) ========
    gemm_att<32><<<dim3(gemmRows, 2), 256, 0, stream>>>(h1, W3, xl, att3_src, att3_dst,
                                                        a_s, a_d, NN, 64, NH * 32);
    softmax_csr<true><<<NB4, 256, 0, stream>>>(rowptr, psrc, perm, a_s, a_d, alpha_p, an2);
    aggregate_w128<<<NB4, 256, 0, stream>>>(rowptr, psrc, alpha_p, xl, b3, out_nodes);

    // ======== Edge MLP (tile-GEMM) ========
    edge_mlp_gemm<<<EE / TE, 128, 0, stream>>>(out_nodes, an2, ei, mW1, mb1, mW2, mb2, out_edges);
}